// Round 1
// baseline (795.539 us; speedup 1.0000x reference)
//
#include <hip/hip_runtime.h>
#include <hip/hip_bf16.h>

// CCAttention on MI355X. Pipeline (all bf16 MFMA 16x16x32, fp32 stats):
//  k_mean -> k_wcvt -> k_gate -> k_qkv -> k_stats(col,row) -> k_comb
//  -> k_attout(col->outH^T, row->outW) -> k_final (transpose+combine).
// ws usage ~341 MB.

#define BB 8
#define CC 288
#define CQn 36
#define CQP 64
#define HH 128
#define WW 128
#define HWn (HH*WW)
#define MR 368  // 288 v rows + 36 q + 36 k + 8 pad = 23 MFMA m-tiles

typedef __attribute__((ext_vector_type(8))) short bf16x8;
typedef __attribute__((ext_vector_type(4))) float f32x4;

static __device__ __forceinline__ unsigned short f2bf(float f) {
  __hip_bfloat16 h = __float2bfloat16(f);
  return __builtin_bit_cast(unsigned short, h);
}
static __device__ __forceinline__ float bf2f(unsigned short u) {
  unsigned int v = ((unsigned int)u) << 16;
  return __builtin_bit_cast(float, v);
}

// ---------------- per-(b,c) mean over (h,w) ----------------
__global__ void k_mean(const float* __restrict__ x, float* __restrict__ y) {
  int bc = blockIdx.x;
  const f32x4* p = (const f32x4*)(x + (size_t)bc * HWn);
  int t = threadIdx.x;
  float s = 0.f;
#pragma unroll
  for (int i = 0; i < 16; ++i) {
    f32x4 v = p[t + i * 256];
    s += v[0] + v[1] + v[2] + v[3];
  }
  s += __shfl_xor(s, 1);  s += __shfl_xor(s, 2);  s += __shfl_xor(s, 4);
  s += __shfl_xor(s, 8);  s += __shfl_xor(s, 16); s += __shfl_xor(s, 32);
  __shared__ float ls[4];
  if ((t & 63) == 0) ls[t >> 6] = s;
  __syncthreads();
  if (t == 0) y[bc] = (ls[0] + ls[1] + ls[2] + ls[3]) * (1.f / HWn);
}

// -------- pack weights: rows 0..287 Wv, 288..323 Wq, 324..359 Wk, 360..367 zero --------
__global__ void k_wcvt(const float* __restrict__ Wq, const float* __restrict__ Wk,
                       const float* __restrict__ Wv, const float* __restrict__ bq,
                       const float* __restrict__ bk, const float* __restrict__ bv,
                       unsigned short* __restrict__ Wcat, float* __restrict__ bcat) {
  int gid = blockIdx.x * 256 + threadIdx.x;
  int total = MR * CC;
  for (int i = gid; i < total; i += gridDim.x * 256) {
    int r = i / CC, c = i - r * CC;
    float v;
    if (r < 288) v = Wv[r * CC + c];
    else if (r < 324) v = Wq[(r - 288) * CC + c];
    else if (r < 360) v = Wk[(r - 324) * CC + c];
    else v = 0.f;
    Wcat[i] = f2bf(v);
  }
  if (gid < MR) {
    float bb;
    if (gid < 288) bb = bv[gid];
    else if (gid < 324) bb = bq[gid - 288];
    else if (gid < 360) bb = bk[gid - 324];
    else bb = 0.f;
    bcat[gid] = bb;
  }
}

// ---------------- ECA gate ----------------
__global__ void k_gate(const float* __restrict__ y, const float* __restrict__ eca,
                       float* __restrict__ gate) {
  int i = blockIdx.x * 256 + threadIdx.x;
  if (i >= BB * CC) return;
  int c = i % CC;
  float l = (c > 0)      ? y[i - 1] : 0.f;
  float r = (c < CC - 1) ? y[i + 1] : 0.f;
  float yc = eca[0] * l + eca[1] * y[i] + eca[2] * r;
  gate[i] = 1.f / (1.f + __expf(-yc));
}

// ---------------- QKV projection GEMM ----------------
// grid 1024: tile = 16h x 8w pixels (p = hl*8 + wl), M = 368 rows, K = 288.
__global__ __launch_bounds__(256, 2) void k_qkv(
    const float* __restrict__ x, const unsigned short* __restrict__ Wcat,
    const float* __restrict__ bcat,
    unsigned short* __restrict__ vstd, unsigned short* __restrict__ vT,
    unsigned short* __restrict__ qpix, unsigned short* __restrict__ kpix) {
  int blk = blockIdx.x;
  int b = blk >> 7, th = (blk >> 4) & 7, tw = blk & 15;
  int h0 = th * 16, w0 = tw * 8;
  int t = threadIdx.x;
  int lane = t & 63, wv = t >> 6;
  int l16 = lane & 15, lg = lane >> 4;

  __shared__ unsigned short xh[2][128][40];   // [pixel][channel^swz], bf16
  __shared__ unsigned short resg[96][136];    // epilogue restage

  f32x4 acc[23][2];
#pragma unroll
  for (int m = 0; m < 23; ++m) {
    acc[m][0] = {0.f, 0.f, 0.f, 0.f};
    acc[m][1] = {0.f, 0.f, 0.f, 0.f};
  }

  f32x4 ld[4];
  auto issue_loads = [&](int kc) {
#pragma unroll
    for (int i = 0; i < 4; ++i) {
      int qid = i * 256 + t;
      int c = qid >> 5, rem = qid & 31, hl = rem >> 1, wq = rem & 1;
      ld[i] = *(const f32x4*)(x + (((size_t)(b * CC + kc * 32 + c) * HH + h0 + hl) * WW + w0 + wq * 4));
    }
  };
  auto store_stage = [&](int buf) {
#pragma unroll
    for (int i = 0; i < 4; ++i) {
      int qid = i * 256 + t;
      int c = qid >> 5, rem = qid & 31, hl = rem >> 1, wq = rem & 1;
      int pb = hl * 8 + wq * 4;
#pragma unroll
      for (int e = 0; e < 4; ++e) {
        int p = pb + e;
        int cs = c ^ (((p >> 2) & 3) << 3);   // bank swizzle, keeps 8-runs contiguous
        xh[buf][p][cs] = f2bf(ld[i][e]);
      }
    }
  };

  issue_loads(0);
  store_stage(0);
  __syncthreads();

  for (int kc = 0; kc < 9; ++kc) {
    if (kc < 8) issue_loads(kc + 1);
    int buf = kc & 1;
    bf16x8 bfr[2];
#pragma unroll
    for (int nt = 0; nt < 2; ++nt) {
      int p = (wv * 2 + nt) * 16 + l16;
      int coff = (lg * 8) ^ (((p >> 2) & 3) << 3);
      bfr[nt] = *(const bf16x8*)&xh[buf][p][coff];
    }
#pragma unroll
    for (int mt = 0; mt < 23; ++mt) {
      bf16x8 af = *(const bf16x8*)(Wcat + ((size_t)(mt * 16 + l16) * CC + kc * 32 + lg * 8));
      acc[mt][0] = __builtin_amdgcn_mfma_f32_16x16x32_bf16(af, bfr[0], acc[mt][0], 0, 0, 0);
      acc[mt][1] = __builtin_amdgcn_mfma_f32_16x16x32_bf16(af, bfr[1], acc[mt][1], 0, 0, 0);
    }
    if (kc < 8) store_stage(buf ^ 1);
    __syncthreads();
  }

  // ---- epilogue: v channels, 3 chunks of 96 ----
#pragma unroll
  for (int chunk = 0; chunk < 3; ++chunk) {
    __syncthreads();
#pragma unroll
    for (int mi = 0; mi < 6; ++mi) {
      int mt = chunk * 6 + mi;
#pragma unroll
      for (int nt = 0; nt < 2; ++nt) {
        int n = (wv * 2 + nt) * 16 + l16;
#pragma unroll
        for (int j = 0; j < 4; ++j) {
          int ch = mt * 16 + lg * 4 + j;
          resg[mi * 16 + lg * 4 + j][n] = f2bf(acc[mt][nt][j] + bcat[ch]);
        }
      }
    }
    __syncthreads();
#pragma unroll
    for (int i = 0; i < 6; ++i) {           // v std layout (B,C,H,W)
      int task = i * 256 + t;
      int cpr = task >> 4, hl = task & 15;
      uint4 val = *(const uint4*)&resg[cpr][hl * 8];
      int ch = chunk * 96 + cpr;
      *(uint4*)(vstd + (((size_t)(b * CC + ch) * HH + h0 + hl) * WW + w0)) = val;
    }
#pragma unroll
    for (int i = 0; i < 6; ++i) {           // v transposed (B,W,C,H)
      int task = i * 256 + t;
      int cpr = task >> 4, wl = (task >> 1) & 7, hs = task & 1;
      unsigned int uu[4];
#pragma unroll
      for (int e2 = 0; e2 < 4; ++e2) {
        unsigned int lo = resg[cpr][(hs * 8 + 2 * e2) * 8 + wl];
        unsigned int hi = resg[cpr][(hs * 8 + 2 * e2 + 1) * 8 + wl];
        uu[e2] = lo | (hi << 16);
      }
      uint4 val; val.x = uu[0]; val.y = uu[1]; val.z = uu[2]; val.w = uu[3];
      int ch = chunk * 96 + cpr;
      *(uint4*)(vT + (((size_t)(b * WW + w0 + wl) * CC + ch) * HH + h0 + hs * 8)) = val;
    }
  }

  // ---- epilogue: q/k -> pixel-major (B,W,H,64) with zero pad ----
  __syncthreads();
#pragma unroll
  for (int mi = 0; mi < 5; ++mi) {
    int mt = 18 + mi;
#pragma unroll
    for (int nt = 0; nt < 2; ++nt) {
      int n = (wv * 2 + nt) * 16 + l16;
#pragma unroll
      for (int j = 0; j < 4; ++j) {
        int rr = mi * 16 + lg * 4 + j;
        if (rr < 72) resg[rr][n] = f2bf(acc[mt][nt][j] + bcat[288 + rr]);
      }
    }
  }
  __syncthreads();
  {
    int px = t >> 1, tensor = t & 1;
    int hl = px >> 3, wl = px & 7;
    unsigned int uu[32];
#pragma unroll
    for (int e = 0; e < 32; ++e) {
      unsigned int lo = (2 * e < CQn)     ? (unsigned int)resg[tensor * CQn + 2 * e][px]     : 0u;
      unsigned int hi = (2 * e + 1 < CQn) ? (unsigned int)resg[tensor * CQn + 2 * e + 1][px] : 0u;
      uu[e] = lo | (hi << 16);
    }
    unsigned short* dst = (tensor ? kpix : qpix) +
                          ((size_t)((b * WW + w0 + wl) * HH + h0 + hl)) * CQP;
#pragma unroll
    for (int e2 = 0; e2 < 8; ++e2) {
      uint4 val; val.x = uu[e2 * 4]; val.y = uu[e2 * 4 + 1];
      val.z = uu[e2 * 4 + 2]; val.w = uu[e2 * 4 + 3];
      ((uint4*)dst)[e2] = val;
    }
  }
}

// ---------------- per-line logit stats (variant 0 = column w/ diag mask, 1 = row) ----------------
__global__ __launch_bounds__(256, 2) void k_stats(
    const unsigned short* __restrict__ qpix, const unsigned short* __restrict__ kpix,
    float* __restrict__ mout, float* __restrict__ sout, int variant) {
  int line = blockIdx.x;
  int b = line >> 7, r = line & 127;
  size_t qbase; int pstride;
  if (variant == 0) { qbase = (size_t)line * (HH * CQP); pstride = CQP; }
  else { qbase = (size_t)b * (WW * HH * CQP) + (size_t)r * CQP; pstride = HH * CQP; }
  const unsigned short* qb = qpix + qbase;
  const unsigned short* kb = kpix + qbase;
  int t = threadIdx.x, lane = t & 63, wv = t >> 6, l16 = lane & 15, lg = lane >> 4;

  f32x4 e[2][8];
#pragma unroll
  for (int pt = 0; pt < 2; ++pt)
#pragma unroll
    for (int Ht = 0; Ht < 8; ++Ht) e[pt][Ht] = {0.f, 0.f, 0.f, 0.f};

#pragma unroll
  for (int ks = 0; ks < 2; ++ks) {
    bf16x8 af[2];
#pragma unroll
    for (int pt = 0; pt < 2; ++pt)
      af[pt] = *(const bf16x8*)(qb + (size_t)((wv * 2 + pt) * 16 + l16) * pstride + ks * 32 + lg * 8);
#pragma unroll
    for (int Ht = 0; Ht < 8; ++Ht) {
      bf16x8 bfr = *(const bf16x8*)(kb + (size_t)(Ht * 16 + l16) * pstride + ks * 32 + lg * 8);
      e[0][Ht] = __builtin_amdgcn_mfma_f32_16x16x32_bf16(af[0], bfr, e[0][Ht], 0, 0, 0);
      e[1][Ht] = __builtin_amdgcn_mfma_f32_16x16x32_bf16(af[1], bfr, e[1][Ht], 0, 0, 0);
    }
  }

#pragma unroll
  for (int pt = 0; pt < 2; ++pt) {
    float mv[4], sv[4];
#pragma unroll
    for (int j = 0; j < 4; ++j) {
      int row = (wv * 2 + pt) * 16 + lg * 4 + j;
      float m = -3.0e38f;
#pragma unroll
      for (int Ht = 0; Ht < 8; ++Ht) {
        int col = Ht * 16 + l16;
        float ev = e[pt][Ht][j];
        if (variant == 0 && row == col) { ev = -1.0e30f; e[pt][Ht][j] = ev; }
        m = fmaxf(m, ev);
      }
      m = fmaxf(m, __shfl_xor(m, 1)); m = fmaxf(m, __shfl_xor(m, 2));
      m = fmaxf(m, __shfl_xor(m, 4)); m = fmaxf(m, __shfl_xor(m, 8));
      float s = 0.f;
#pragma unroll
      for (int Ht = 0; Ht < 8; ++Ht) s += __expf(e[pt][Ht][j] - m);
      s += __shfl_xor(s, 1); s += __shfl_xor(s, 2);
      s += __shfl_xor(s, 4); s += __shfl_xor(s, 8);
      mv[j] = m; sv[j] = s;
    }
    if (l16 == 0) {
#pragma unroll
      for (int j = 0; j < 4; ++j) {
        int row = (wv * 2 + pt) * 16 + lg * 4 + j;
        mout[(size_t)line * 128 + row] = mv[j];
        sout[(size_t)line * 128 + row] = sv[j];
      }
    }
  }
}

// ---------------- merge col/row stats per pixel ----------------
__global__ void k_comb(const float* __restrict__ mcol, const float* __restrict__ scol,
                       const float* __restrict__ mrow, const float* __restrict__ srow,
                       float* __restrict__ mf, float* __restrict__ rzf,
                       float* __restrict__ mg, float* __restrict__ rzg) {
  int idx = blockIdx.x * 256 + threadIdx.x;
  int b = idx >> 14;
  int hw = idx & 16383;
  int h = hw >> 7, w = hw & 127;
  int cidx = (b << 14) + (w << 7) + h;
  float mc = mcol[cidx], sc = scol[cidx];
  float mr = mrow[idx],  sr = srow[idx];
  float m = fmaxf(mc, mr);
  float Z = sc * __expf(mc - m) + sr * __expf(mr - m);
  float rz = 1.f / Z;
  mg[idx] = m;  rzg[idx] = rz;
  mf[cidx] = m; rzf[cidx] = rz;
}

// ---------------- attention output (variant 0 = column -> outH^T, 1 = row -> outW std) ----------------
__global__ __launch_bounds__(256, 2) void k_attout(
    const unsigned short* __restrict__ qpix, const unsigned short* __restrict__ kpix,
    const unsigned short* __restrict__ vsrc, unsigned short* __restrict__ outp,
    const float* __restrict__ mstat, const float* __restrict__ rzstat, int variant) {
  int line = blockIdx.x;
  int b = line >> 7, r = line & 127;
  size_t qbase, vbase; int pstride, vstride, ostride;
  if (variant == 0) {
    qbase = (size_t)line * (HH * CQP); pstride = CQP;
    vbase = (size_t)line * (CC * HH);  vstride = HH;  ostride = HH;
  } else {
    qbase = (size_t)b * (WW * HH * CQP) + (size_t)r * CQP; pstride = HH * CQP;
    vbase = (size_t)b * (CC * HWn) + (size_t)r * WW;       vstride = HWn; ostride = HWn;
  }
  const unsigned short* qb = qpix + qbase;
  const unsigned short* kb = kpix + qbase;
  const float* mb  = mstat  + (size_t)line * 128;
  const float* rzb = rzstat + (size_t)line * 128;
  int t = threadIdx.x, lane = t & 63, wv = t >> 6, l16 = lane & 15, lg = lane >> 4;

  __shared__ unsigned short attld[4][32][136];  // per-wave att rows
  __shared__ unsigned short resg[4][48][40];    // per-wave output restage

  // E = Q^T K (per-wave: 2 pixel-tiles x 8 key-tiles)
  f32x4 e[2][8];
#pragma unroll
  for (int pt = 0; pt < 2; ++pt)
#pragma unroll
    for (int Ht = 0; Ht < 8; ++Ht) e[pt][Ht] = {0.f, 0.f, 0.f, 0.f};
#pragma unroll
  for (int ks = 0; ks < 2; ++ks) {
    bf16x8 af[2];
#pragma unroll
    for (int pt = 0; pt < 2; ++pt)
      af[pt] = *(const bf16x8*)(qb + (size_t)((wv * 2 + pt) * 16 + l16) * pstride + ks * 32 + lg * 8);
#pragma unroll
    for (int Ht = 0; Ht < 8; ++Ht) {
      bf16x8 bfr = *(const bf16x8*)(kb + (size_t)(Ht * 16 + l16) * pstride + ks * 32 + lg * 8);
      e[0][Ht] = __builtin_amdgcn_mfma_f32_16x16x32_bf16(af[0], bfr, e[0][Ht], 0, 0, 0);
      e[1][Ht] = __builtin_amdgcn_mfma_f32_16x16x32_bf16(af[1], bfr, e[1][Ht], 0, 0, 0);
    }
  }

  // att = exp(e - m) / Z -> LDS (bf16)
#pragma unroll
  for (int pt = 0; pt < 2; ++pt) {
#pragma unroll
    for (int j = 0; j < 4; ++j) {
      int rowg = (wv * 2 + pt) * 16 + lg * 4 + j;
      float m = mb[rowg], rz = rzb[rowg];
#pragma unroll
      for (int Ht = 0; Ht < 8; ++Ht) {
        int col = Ht * 16 + l16;
        float ev = e[pt][Ht][j];
        if (variant == 0 && rowg == col) ev = -1.0e30f;
        attld[wv][pt * 16 + lg * 4 + j][col] = f2bf(__expf(ev - m) * rz);
      }
    }
  }
  __syncthreads();

  // AV: 6 chunks of 3 channel-tiles, K = 128 line pixels
#pragma unroll
  for (int chunk = 0; chunk < 6; ++chunk) {
    f32x4 o[3][2];
#pragma unroll
    for (int mi = 0; mi < 3; ++mi) { o[mi][0] = {0.f,0.f,0.f,0.f}; o[mi][1] = {0.f,0.f,0.f,0.f}; }
#pragma unroll
    for (int kc = 0; kc < 4; ++kc) {
      bf16x8 bfr[2];
#pragma unroll
      for (int nt = 0; nt < 2; ++nt)
        bfr[nt] = *(const bf16x8*)&attld[wv][nt * 16 + l16][kc * 32 + lg * 8];
#pragma unroll
      for (int mi = 0; mi < 3; ++mi) {
        int mt = chunk * 3 + mi;
        bf16x8 af = *(const bf16x8*)(vsrc + vbase + (size_t)(mt * 16 + l16) * vstride + kc * 32 + lg * 8);
        o[mi][0] = __builtin_amdgcn_mfma_f32_16x16x32_bf16(af, bfr[0], o[mi][0], 0, 0, 0);
        o[mi][1] = __builtin_amdgcn_mfma_f32_16x16x32_bf16(af, bfr[1], o[mi][1], 0, 0, 0);
      }
    }
#pragma unroll
    for (int mi = 0; mi < 3; ++mi)
#pragma unroll
      for (int nt = 0; nt < 2; ++nt) {
        int nl = nt * 16 + l16;
#pragma unroll
        for (int j = 0; j < 4; ++j)
          resg[wv][mi * 16 + lg * 4 + j][nl] = f2bf(o[mi][nt][j]);
      }
    __syncthreads();
#pragma unroll
    for (int i = 0; i < 3; ++i) {
      int task = i * 64 + lane;
      int cpr = task >> 2, seg = task & 3;
      uint4 val = *(const uint4*)&resg[wv][cpr][seg * 8];
      int ch = chunk * 48 + cpr;
      *(uint4*)(outp + vbase + (size_t)ch * ostride + wv * 32 + seg * 8) = val;
    }
  }
}

// ---------------- final combine: gamma*(outH + outW + x*gate) + x ----------------
__global__ void k_final(const unsigned short* __restrict__ outHT,
                        const unsigned short* __restrict__ outWs,
                        const float* __restrict__ x, const float* __restrict__ gate,
                        const float* __restrict__ gammap, float* __restrict__ out) {
  int blk = blockIdx.x;
  int b = blk / 1152;
  int rr = blk - b * 1152;
  int c = rr >> 2, h0 = (rr & 3) * 32;
  int t = threadIdx.x;
  __shared__ unsigned short ldsT[128][40];
#pragma unroll
  for (int i = 0; i < 2; ++i) {
    int task = i * 256 + t;
    int w = task >> 2, hq = task & 3;
    uint4 v = *(const uint4*)(outHT + ((size_t)(b * WW + w) * CC + c) * HH + h0 + hq * 8);
    *(uint4*)&ldsT[w][hq * 8] = v;
  }
  __syncthreads();
  float gm = gammap[0];
  float g = gate[b * CC + c];
  size_t rowbase = (size_t)(b * CC + c) * HH;
#pragma unroll
  for (int i = 0; i < 2; ++i) {
    int task = i * 256 + t;
    int hl = task >> 4, wq = task & 15;
    size_t goff = (rowbase + h0 + hl) * WW + wq * 8;
    uint4 ow4 = *(const uint4*)(outWs + goff);
    f32x4 x1 = *(const f32x4*)(x + goff);
    f32x4 x2 = *(const f32x4*)(x + goff + 4);
    unsigned int owu[4] = {ow4.x, ow4.y, ow4.z, ow4.w};
    f32x4 r1, r2;
#pragma unroll
    for (int e2 = 0; e2 < 8; ++e2) {
      float oh = bf2f(ldsT[wq * 8 + e2][hl]);
      unsigned int pair = owu[e2 >> 1];
      float ow = bf2f((unsigned short)((e2 & 1) ? (pair >> 16) : (pair & 0xffffu)));
      float xv = (e2 < 4) ? x1[e2 & 3] : x2[e2 & 3];
      float res = gm * (oh + ow + xv * g) + xv;
      if (e2 < 4) r1[e2 & 3] = res; else r2[e2 & 3] = res;
    }
    *(f32x4*)(out + goff) = r1;
    *(f32x4*)(out + goff + 4) = r2;
  }
}

extern "C" void kernel_launch(void* const* d_in, const int* in_sizes, int n_in,
                              void* d_out, int out_size, void* d_ws, size_t ws_size,
                              hipStream_t stream) {
  (void)in_sizes; (void)n_in; (void)out_size; (void)ws_size;
  const float* x     = (const float*)d_in[0];
  const float* Wq    = (const float*)d_in[1];
  const float* bq    = (const float*)d_in[2];
  const float* Wk    = (const float*)d_in[3];
  const float* bk    = (const float*)d_in[4];
  const float* Wv    = (const float*)d_in[5];
  const float* bv    = (const float*)d_in[6];
  const float* eca   = (const float*)d_in[7];
  const float* gamma = (const float*)d_in[8];
  float* out = (float*)d_out;

  char* p = (char*)d_ws;
  auto take = [&](size_t bytes) {
    char* r = p;
    p += (bytes + 255) & ~(size_t)255;
    return r;
  };
  unsigned short* qpix  = (unsigned short*)take((size_t)BB * HWn * CQP * 2);
  unsigned short* kpix  = (unsigned short*)take((size_t)BB * HWn * CQP * 2);
  unsigned short* vstd  = (unsigned short*)take((size_t)BB * CC * HWn * 2);
  unsigned short* vT    = (unsigned short*)take((size_t)BB * CC * HWn * 2);
  unsigned short* outHT = (unsigned short*)take((size_t)BB * CC * HWn * 2);
  unsigned short* outWs = (unsigned short*)take((size_t)BB * CC * HWn * 2);
  float* mcol = (float*)take((size_t)BB * HWn * 4);
  float* scol = (float*)take((size_t)BB * HWn * 4);
  float* mrow = (float*)take((size_t)BB * HWn * 4);
  float* srow = (float*)take((size_t)BB * HWn * 4);
  float* mf   = (float*)take((size_t)BB * HWn * 4);
  float* rzf  = (float*)take((size_t)BB * HWn * 4);
  float* mg   = (float*)take((size_t)BB * HWn * 4);
  float* rzg  = (float*)take((size_t)BB * HWn * 4);
  unsigned short* Wcat = (unsigned short*)take((size_t)MR * CC * 2);
  float* bcat = (float*)take((size_t)MR * 4);
  float* y    = (float*)take((size_t)BB * CC * 4);
  float* gate = (float*)take((size_t)BB * CC * 4);

  k_mean<<<dim3(BB * CC), dim3(256), 0, stream>>>(x, y);
  k_wcvt<<<dim3(128), dim3(256), 0, stream>>>(Wq, Wk, Wv, bq, bk, bv, Wcat, bcat);
  k_gate<<<dim3(9), dim3(256), 0, stream>>>(y, eca, gate);
  k_qkv<<<dim3(1024), dim3(256), 0, stream>>>(x, Wcat, bcat, vstd, vT, qpix, kpix);
  k_stats<<<dim3(1024), dim3(256), 0, stream>>>(qpix, kpix, mcol, scol, 0);
  k_stats<<<dim3(1024), dim3(256), 0, stream>>>(qpix, kpix, mrow, srow, 1);
  k_comb<<<dim3(512), dim3(256), 0, stream>>>(mcol, scol, mrow, srow, mf, rzf, mg, rzg);
  k_attout<<<dim3(1024), dim3(256), 0, stream>>>(qpix, kpix, vT, outHT, mf, rzf, 0);
  k_attout<<<dim3(1024), dim3(256), 0, stream>>>(qpix, kpix, vstd, outWs, mg, rzg, 1);
  k_final<<<dim3(BB * CC * 4), dim3(256), 0, stream>>>(outHT, outWs, x, gate, gamma, out);
}

// Round 3
// 651.356 us; speedup vs baseline: 1.2214x; 1.2214x over previous
//
#include <hip/hip_runtime.h>
#include <hip/hip_bf16.h>

// CCAttention on MI355X. Pipeline:
//  k_wcvt, k_xT(+mean) -> k_gate -> k_qkv (GEMM from pixel-major x) -> k_vT
//  -> k_stats(col,row) -> k_comb -> k_attout(col->outH^T, row->outW) -> k_final.

#define BB 8
#define CC 288
#define CQn 36
#define CQP 64
#define HH 128
#define WW 128
#define HWn (HH*WW)
#define MR 384  // 288 v rows + 36 q + 36 k + 24 pad = 3 M-tiles of 128

typedef __attribute__((ext_vector_type(8))) short bf16x8;
typedef __attribute__((ext_vector_type(4))) float f32x4;

static __device__ __forceinline__ unsigned short f2bf(float f) {
  __hip_bfloat16 h = __float2bfloat16(f);
  return __builtin_bit_cast(unsigned short, h);
}
static __device__ __forceinline__ float bf2f(unsigned short u) {
  unsigned int v = ((unsigned int)u) << 16;
  return __builtin_bit_cast(float, v);
}

// -------- pack weights: rows 0..287 Wv, 288..323 Wq, 324..359 Wk, 360..383 zero --------
__global__ void k_wcvt(const float* __restrict__ Wq, const float* __restrict__ Wk,
                       const float* __restrict__ Wv, const float* __restrict__ bq,
                       const float* __restrict__ bk, const float* __restrict__ bv,
                       unsigned short* __restrict__ Wcat, float* __restrict__ bcat) {
  int gid = blockIdx.x * 256 + threadIdx.x;
  int total = MR * CC;
  for (int i = gid; i < total; i += gridDim.x * 256) {
    int r = i / CC, c = i - r * CC;
    float v;
    if (r < 288) v = Wv[r * CC + c];
    else if (r < 324) v = Wq[(r - 288) * CC + c];
    else if (r < 360) v = Wk[(r - 324) * CC + c];
    else v = 0.f;
    Wcat[i] = f2bf(v);
  }
  if (gid < MR) {
    float bb;
    if (gid < 288) bb = bv[gid];
    else if (gid < 324) bb = bq[gid - 288];
    else if (gid < 360) bb = bk[gid - 324];
    else bb = 0.f;
    bcat[gid] = bb;
  }
}

// -------- x (B,C,H,W) f32 -> xpix (B,HW,C) bf16, fused per-channel sum (for mean) --------
__global__ __launch_bounds__(256) void k_xT(const float* __restrict__ x,
                                            unsigned short* __restrict__ xpix,
                                            float* __restrict__ ysum) {
  int blk = blockIdx.x;                // 2048 = B * 256
  int b = blk >> 8, px0 = (blk & 255) * 64;
  int t = threadIdx.x;
  __shared__ unsigned short lx[64][296];
  const float* xb = x + (size_t)b * CC * HWn + px0;
#pragma unroll
  for (int i = 0; i < 18; ++i) {
    int qid = i * 256 + t;
    int c = qid >> 4, seg = qid & 15;
    f32x4 v = *(const f32x4*)(xb + (size_t)c * HWn + seg * 4);
#pragma unroll
    for (int e = 0; e < 4; ++e) lx[seg * 4 + e][c] = f2bf(v[e]);
  }
  __syncthreads();
  // coalesced pixel-major store: 64 px x 288 ch, 4 threads per px
  {
    int px = t >> 2, part = t & 3;
    unsigned short* dst = xpix + ((size_t)(b * HWn) + px0 + px) * CC + part * 72;
    const uint4* src = (const uint4*)&lx[px][part * 72];
#pragma unroll
    for (int j = 0; j < 9; ++j) ((uint4*)dst)[j] = src[j];
  }
  // per-channel partial sums (bf16-rounded inputs; error ~3e-5 on the mean)
  for (int cc = t; cc < CC; cc += 256) {
    float s = 0.f;
#pragma unroll
    for (int px = 0; px < 64; ++px) s += bf2f(lx[px][cc]);
    atomicAdd(&ysum[b * CC + cc], s);
  }
}

// ---------------- ECA gate (ysum holds per-channel SUM over HW) ----------------
__global__ void k_gate(const float* __restrict__ y, const float* __restrict__ eca,
                       float* __restrict__ gate) {
  int i = blockIdx.x * 256 + threadIdx.x;
  if (i >= BB * CC) return;
  int c = i % CC;
  const float sc = 1.f / HWn;
  float l = (c > 0)      ? y[i - 1] * sc : 0.f;
  float r = (c < CC - 1) ? y[i + 1] * sc : 0.f;
  float yc = eca[0] * l + eca[1] * y[i] * sc + eca[2] * r;
  gate[i] = 1.f / (1.f + __expf(-yc));
}

// ---------------- QKV projection GEMM ----------------
// grid 1536 = 512 n-tiles (256 px = 2 h-rows) x 3 m-tiles (128 rows of Wcat).
// Main loop is LDS-free: A/B frags direct from L2/L3-resident Wcat/xpix.
__global__ __launch_bounds__(256, 2) void k_qkv(
    const unsigned short* __restrict__ xpix, const unsigned short* __restrict__ Wcat,
    const float* __restrict__ bcat,
    unsigned short* __restrict__ vstd,
    unsigned short* __restrict__ qpix, unsigned short* __restrict__ kpix) {
  int blk = blockIdx.x;
  int mb = blk % 3;
  int nt = blk / 3;
  int b = nt >> 6;
  int pxb = (nt & 63) * 256;          // 2 h-rows, full width
  int t = threadIdx.x, lane = t & 63, wv = t >> 6;
  int wm = wv >> 1, wn = wv & 1;
  int l16 = lane & 15, lg = lane >> 4;

  const unsigned short* xb = xpix + ((size_t)b * HWn + pxb) * CC;
  const unsigned short* wb = Wcat + (size_t)(mb * 128) * CC;

  __shared__ unsigned short eps[72][280];

  f32x4 acc[4][8];
#pragma unroll
  for (int mi = 0; mi < 4; ++mi)
#pragma unroll
    for (int ni = 0; ni < 8; ++ni) acc[mi][ni] = {0.f, 0.f, 0.f, 0.f};

  for (int kc = 0; kc < 9; ++kc) {
    int ko = kc * 32 + lg * 8;
    bf16x8 af[4], bf[8];
#pragma unroll
    for (int mi = 0; mi < 4; ++mi)
      af[mi] = *(const bf16x8*)(wb + (size_t)(wm * 64 + mi * 16 + l16) * CC + ko);
#pragma unroll
    for (int ni = 0; ni < 8; ++ni)
      bf[ni] = *(const bf16x8*)(xb + (size_t)(wn * 128 + ni * 16 + l16) * CC + ko);
#pragma unroll
    for (int mi = 0; mi < 4; ++mi)
#pragma unroll
      for (int ni = 0; ni < 8; ++ni)
        acc[mi][ni] = __builtin_amdgcn_mfma_f32_16x16x32_bf16(af[mi], bf[ni], acc[mi][ni], 0, 0, 0);
  }

  // ---- v epilogue: 4 chunks of 32 channel-rows, LDS restage -> 512B runs ----
#pragma unroll
  for (int ch_i = 0; ch_i < 4; ++ch_i) {
    int r0 = mb * 128 + ch_i * 32;    // global Wcat row of chunk start
    __syncthreads();
    if (r0 < 288 && wm == (ch_i >> 1)) {
      int mibase = (ch_i & 1) * 2;
#pragma unroll
      for (int mr = 0; mr < 2; ++mr) {
#pragma unroll
        for (int ni = 0; ni < 8; ++ni) {
#pragma unroll
          for (int j = 0; j < 4; ++j) {
            int rrel = mr * 16 + lg * 4 + j;
            eps[rrel][wn * 128 + ni * 16 + l16] =
                f2bf(acc[mibase + mr][ni][j] + bcat[r0 + rrel]);
          }
        }
      }
    }
    __syncthreads();
    if (r0 < 288) {
      int row = t >> 3, part = t & 7;  // 32 rows x 8 parts of 32 px
      unsigned short* dst = vstd + (size_t)(b * CC + r0 + row) * HWn + pxb + part * 32;
      const uint4* src = (const uint4*)&eps[row][part * 32];
#pragma unroll
      for (int j = 0; j < 4; ++j) ((uint4*)dst)[j] = src[j];
    }
  }

  // ---- q/k epilogue (mb==2 only): rows rel 0..35 = q, 36..71 = k ----
  if (mb == 2) {
    __syncthreads();
    if (wm == 0) {
#pragma unroll
      for (int mr = 0; mr < 2; ++mr)
#pragma unroll
        for (int ni = 0; ni < 8; ++ni)
#pragma unroll
          for (int j = 0; j < 4; ++j) {
            int rel = mr * 16 + lg * 4 + j;   // m_local 32..63 -> rel 0..31
            eps[rel][wn * 128 + ni * 16 + l16] =
                f2bf(acc[2 + mr][ni][j] + bcat[288 + rel]);
          }
    } else {
#pragma unroll
      for (int mi = 0; mi < 3; ++mi)
#pragma unroll
        for (int ni = 0; ni < 8; ++ni)
#pragma unroll
          for (int j = 0; j < 4; ++j) {
            int rel = 32 + mi * 16 + lg * 4 + j;  // m_local 64..111 -> rel 32..79
            if (rel < 72)
              eps[rel][wn * 128 + ni * 16 + l16] =
                  f2bf(acc[mi][ni][j] + bcat[288 + rel]);
          }
    }
    __syncthreads();
    {
      int px = t;
      int hl = px >> 7, w = px & 127;
      int h = (pxb >> 7) + hl;
      unsigned int uu[32];
#pragma unroll
      for (int e = 0; e < 18; ++e)
        uu[e] = (unsigned int)eps[2 * e][px] | ((unsigned int)eps[2 * e + 1][px] << 16);
#pragma unroll
      for (int e = 18; e < 32; ++e) uu[e] = 0u;
      unsigned short* dq = qpix + ((size_t)(b * WW + w) * HH + h) * CQP;
#pragma unroll
      for (int e2 = 0; e2 < 8; ++e2) {
        uint4 val; val.x = uu[e2 * 4]; val.y = uu[e2 * 4 + 1];
        val.z = uu[e2 * 4 + 2]; val.w = uu[e2 * 4 + 3];
        ((uint4*)dq)[e2] = val;
      }
#pragma unroll
      for (int e = 0; e < 18; ++e)
        uu[e] = (unsigned int)eps[36 + 2 * e][px] | ((unsigned int)eps[37 + 2 * e][px] << 16);
      unsigned short* dk = kpix + ((size_t)(b * WW + w) * HH + h) * CQP;
#pragma unroll
      for (int e2 = 0; e2 < 8; ++e2) {
        uint4 val; val.x = uu[e2 * 4]; val.y = uu[e2 * 4 + 1];
        val.z = uu[e2 * 4 + 2]; val.w = uu[e2 * 4 + 3];
        ((uint4*)dk)[e2] = val;
      }
    }
  }
}

// -------- vstd (B,C,H,W) bf16 -> vT (B,W,C,H) bf16, LDS tile transpose --------
// Tile: 64 w x 128 h per block. FIXED: full coverage on both load and store.
__global__ __launch_bounds__(256) void k_vT(const unsigned short* __restrict__ vstd,
                                            unsigned short* __restrict__ vT) {
  int blk = blockIdx.x;               // 8*288*2 = 4608
  int b = blk / 576, r = blk - b * 576;
  int c = r >> 1, wh = (r & 1) * 64;
  int t = threadIdx.x;
  __shared__ unsigned short lv[64][136];   // [w][h]
  const unsigned short* src = vstd + (size_t)(b * CC + c) * HWn + wh;
#pragma unroll
  for (int i = 0; i < 4; ++i) {
    int qid = i * 256 + t;              // 1024 tasks = 128 h x 8 segs
    int h = qid >> 3, seg = qid & 7;
    uint4 v = *(const uint4*)(src + (size_t)h * WW + seg * 8);
    const unsigned short* pv = (const unsigned short*)&v;
#pragma unroll
    for (int e = 0; e < 8; ++e) lv[seg * 8 + e][h] = pv[e];
  }
  __syncthreads();
  int w = t >> 2, part = t & 3;         // each thread: 32 h values
  unsigned short* dst = vT + ((size_t)(b * WW + wh + w) * CC + c) * HH + part * 32;
  const uint4* srcl = (const uint4*)&lv[w][part * 32];
#pragma unroll
  for (int j = 0; j < 4; ++j) ((uint4*)dst)[j] = srcl[j];
}

// ---------------- per-line logit stats (variant 0 = column w/ diag mask, 1 = row) ----------------
__global__ __launch_bounds__(256, 2) void k_stats(
    const unsigned short* __restrict__ qpix, const unsigned short* __restrict__ kpix,
    float* __restrict__ mout, float* __restrict__ sout, int variant) {
  int line = blockIdx.x;
  int b = line >> 7, r = line & 127;
  size_t qbase; int pstride;
  if (variant == 0) { qbase = (size_t)line * (HH * CQP); pstride = CQP; }
  else { qbase = (size_t)b * (WW * HH * CQP) + (size_t)r * CQP; pstride = HH * CQP; }
  const unsigned short* qb = qpix + qbase;
  const unsigned short* kb = kpix + qbase;
  int t = threadIdx.x, lane = t & 63, wv = t >> 6, l16 = lane & 15, lg = lane >> 4;

  f32x4 e[2][8];
#pragma unroll
  for (int pt = 0; pt < 2; ++pt)
#pragma unroll
    for (int Ht = 0; Ht < 8; ++Ht) e[pt][Ht] = {0.f, 0.f, 0.f, 0.f};

#pragma unroll
  for (int ks = 0; ks < 2; ++ks) {
    bf16x8 af[2];
#pragma unroll
    for (int pt = 0; pt < 2; ++pt)
      af[pt] = *(const bf16x8*)(qb + (size_t)((wv * 2 + pt) * 16 + l16) * pstride + ks * 32 + lg * 8);
#pragma unroll
    for (int Ht = 0; Ht < 8; ++Ht) {
      bf16x8 bfr = *(const bf16x8*)(kb + (size_t)(Ht * 16 + l16) * pstride + ks * 32 + lg * 8);
      e[0][Ht] = __builtin_amdgcn_mfma_f32_16x16x32_bf16(af[0], bfr, e[0][Ht], 0, 0, 0);
      e[1][Ht] = __builtin_amdgcn_mfma_f32_16x16x32_bf16(af[1], bfr, e[1][Ht], 0, 0, 0);
    }
  }

#pragma unroll
  for (int pt = 0; pt < 2; ++pt) {
    float mv[4], sv[4];
#pragma unroll
    for (int j = 0; j < 4; ++j) {
      int row = (wv * 2 + pt) * 16 + lg * 4 + j;
      float m = -3.0e38f;
#pragma unroll
      for (int Ht = 0; Ht < 8; ++Ht) {
        int col = Ht * 16 + l16;
        float ev = e[pt][Ht][j];
        if (variant == 0 && row == col) { ev = -1.0e30f; e[pt][Ht][j] = ev; }
        m = fmaxf(m, ev);
      }
      m = fmaxf(m, __shfl_xor(m, 1)); m = fmaxf(m, __shfl_xor(m, 2));
      m = fmaxf(m, __shfl_xor(m, 4)); m = fmaxf(m, __shfl_xor(m, 8));
      float s = 0.f;
#pragma unroll
      for (int Ht = 0; Ht < 8; ++Ht) s += __expf(e[pt][Ht][j] - m);
      s += __shfl_xor(s, 1); s += __shfl_xor(s, 2);
      s += __shfl_xor(s, 4); s += __shfl_xor(s, 8);
      mv[j] = m; sv[j] = s;
    }
    if (l16 == 0) {
#pragma unroll
      for (int j = 0; j < 4; ++j) {
        int row = (wv * 2 + pt) * 16 + lg * 4 + j;
        mout[(size_t)line * 128 + row] = mv[j];
        sout[(size_t)line * 128 + row] = sv[j];
      }
    }
  }
}

// ---------------- merge col/row stats per pixel ----------------
__global__ void k_comb(const float* __restrict__ mcol, const float* __restrict__ scol,
                       const float* __restrict__ mrow, const float* __restrict__ srow,
                       float* __restrict__ mf, float* __restrict__ rzf,
                       float* __restrict__ mg, float* __restrict__ rzg) {
  int idx = blockIdx.x * 256 + threadIdx.x;
  int b = idx >> 14;
  int hw = idx & 16383;
  int h = hw >> 7, w = hw & 127;
  int cidx = (b << 14) + (w << 7) + h;
  float mc = mcol[cidx], sc = scol[cidx];
  float mr = mrow[idx],  sr = srow[idx];
  float m = fmaxf(mc, mr);
  float Z = sc * __expf(mc - m) + sr * __expf(mr - m);
  float rz = 1.f / Z;
  mg[idx] = m;  rzg[idx] = rz;
  mf[cidx] = m; rzf[cidx] = rz;
}

// ---------------- attention output (variant 0 = column -> outH^T, 1 = row -> outW std) ----------------
__global__ __launch_bounds__(256, 2) void k_attout(
    const unsigned short* __restrict__ qpix, const unsigned short* __restrict__ kpix,
    const unsigned short* __restrict__ vsrc, unsigned short* __restrict__ outp,
    const float* __restrict__ mstat, const float* __restrict__ rzstat, int variant) {
  int line = blockIdx.x;
  int b = line >> 7, r = line & 127;
  size_t qbase, vbase; int pstride, vstride, ostride;
  if (variant == 0) {
    qbase = (size_t)line * (HH * CQP); pstride = CQP;
    vbase = (size_t)line * (CC * HH);  vstride = HH;  ostride = HH;
  } else {
    qbase = (size_t)b * (WW * HH * CQP) + (size_t)r * CQP; pstride = HH * CQP;
    vbase = (size_t)b * (CC * HWn) + (size_t)r * WW;       vstride = HWn; ostride = HWn;
  }
  const unsigned short* qb = qpix + qbase;
  const unsigned short* kb = kpix + qbase;
  const float* mb  = mstat  + (size_t)line * 128;
  const float* rzb = rzstat + (size_t)line * 128;
  int t = threadIdx.x, lane = t & 63, wv = t >> 6, l16 = lane & 15, lg = lane >> 4;

  __shared__ unsigned short attld[4][32][136];  // per-wave att rows
  __shared__ unsigned short resg[4][48][40];    // per-wave output restage

  f32x4 e[2][8];
#pragma unroll
  for (int pt = 0; pt < 2; ++pt)
#pragma unroll
    for (int Ht = 0; Ht < 8; ++Ht) e[pt][Ht] = {0.f, 0.f, 0.f, 0.f};
#pragma unroll
  for (int ks = 0; ks < 2; ++ks) {
    bf16x8 af[2];
#pragma unroll
    for (int pt = 0; pt < 2; ++pt)
      af[pt] = *(const bf16x8*)(qb + (size_t)((wv * 2 + pt) * 16 + l16) * pstride + ks * 32 + lg * 8);
#pragma unroll
    for (int Ht = 0; Ht < 8; ++Ht) {
      bf16x8 bfr = *(const bf16x8*)(kb + (size_t)(Ht * 16 + l16) * pstride + ks * 32 + lg * 8);
      e[0][Ht] = __builtin_amdgcn_mfma_f32_16x16x32_bf16(af[0], bfr, e[0][Ht], 0, 0, 0);
      e[1][Ht] = __builtin_amdgcn_mfma_f32_16x16x32_bf16(af[1], bfr, e[1][Ht], 0, 0, 0);
    }
  }

#pragma unroll
  for (int pt = 0; pt < 2; ++pt) {
#pragma unroll
    for (int j = 0; j < 4; ++j) {
      int rowg = (wv * 2 + pt) * 16 + lg * 4 + j;
      float m = mb[rowg], rz = rzb[rowg];
#pragma unroll
      for (int Ht = 0; Ht < 8; ++Ht) {
        int col = Ht * 16 + l16;
        float ev = e[pt][Ht][j];
        if (variant == 0 && rowg == col) ev = -1.0e30f;
        attld[wv][pt * 16 + lg * 4 + j][col] = f2bf(__expf(ev - m) * rz);
      }
    }
  }
  __syncthreads();

#pragma unroll
  for (int chunk = 0; chunk < 6; ++chunk) {
    f32x4 o[3][2];
#pragma unroll
    for (int mi = 0; mi < 3; ++mi) { o[mi][0] = {0.f,0.f,0.f,0.f}; o[mi][1] = {0.f,0.f,0.f,0.f}; }
#pragma unroll
    for (int kc = 0; kc < 4; ++kc) {
      bf16x8 bfr[2];
#pragma unroll
      for (int nt = 0; nt < 2; ++nt)
        bfr[nt] = *(const bf16x8*)&attld[wv][nt * 16 + l16][kc * 32 + lg * 8];
#pragma unroll
      for (int mi = 0; mi < 3; ++mi) {
        int mt = chunk * 3 + mi;
        bf16x8 af = *(const bf16x8*)(vsrc + vbase + (size_t)(mt * 16 + l16) * vstride + kc * 32 + lg * 8);
        o[mi][0] = __builtin_amdgcn_mfma_f32_16x16x32_bf16(af, bfr[0], o[mi][0], 0, 0, 0);
        o[mi][1] = __builtin_amdgcn_mfma_f32_16x16x32_bf16(af, bfr[1], o[mi][1], 0, 0, 0);
      }
    }
#pragma unroll
    for (int mi = 0; mi < 3; ++mi)
#pragma unroll
      for (int nt = 0; nt < 2; ++nt) {
        int nl = nt * 16 + l16;
#pragma unroll
        for (int j = 0; j < 4; ++j)
          resg[wv][mi * 16 + lg * 4 + j][nl] = f2bf(o[mi][nt][j]);
      }
    __syncthreads();
#pragma unroll
    for (int i = 0; i < 3; ++i) {
      int task = i * 64 + lane;
      int cpr = task >> 2, seg = task & 3;
      uint4 val = *(const uint4*)&resg[wv][cpr][seg * 8];
      int ch = chunk * 48 + cpr;
      *(uint4*)(outp + vbase + (size_t)ch * ostride + wv * 32 + seg * 8) = val;
    }
  }
}

// ---------------- final combine: gamma*(outH + outW + x*gate) + x ----------------
__global__ void k_final(const unsigned short* __restrict__ outHT,
                        const unsigned short* __restrict__ outWs,
                        const float* __restrict__ x, const float* __restrict__ gate,
                        const float* __restrict__ gammap, float* __restrict__ out) {
  int blk = blockIdx.x;
  int b = blk / 1152;
  int rr = blk - b * 1152;
  int c = rr >> 2, h0 = (rr & 3) * 32;
  int t = threadIdx.x;
  __shared__ unsigned short ldsT[128][40];
#pragma unroll
  for (int i = 0; i < 2; ++i) {
    int task = i * 256 + t;
    int w = task >> 2, hq = task & 3;
    uint4 v = *(const uint4*)(outHT + ((size_t)(b * WW + w) * CC + c) * HH + h0 + hq * 8);
    *(uint4*)&ldsT[w][hq * 8] = v;
  }
  __syncthreads();
  float gm = gammap[0];
  float g = gate[b * CC + c];
  size_t rowbase = (size_t)(b * CC + c) * HH;
#pragma unroll
  for (int i = 0; i < 2; ++i) {
    int task = i * 256 + t;
    int hl = task >> 4, wq = task & 15;
    size_t goff = (rowbase + h0 + hl) * WW + wq * 8;
    uint4 ow4 = *(const uint4*)(outWs + goff);
    f32x4 x1 = *(const f32x4*)(x + goff);
    f32x4 x2 = *(const f32x4*)(x + goff + 4);
    unsigned int owu[4] = {ow4.x, ow4.y, ow4.z, ow4.w};
    f32x4 r1, r2;
#pragma unroll
    for (int e2 = 0; e2 < 8; ++e2) {
      float oh = bf2f(ldsT[wq * 8 + e2][hl]);
      unsigned int pair = owu[e2 >> 1];
      float ow = bf2f((unsigned short)((e2 & 1) ? (pair >> 16) : (pair & 0xffffu)));
      float xv = (e2 < 4) ? x1[e2 & 3] : x2[e2 & 3];
      float res = gm * (oh + ow + xv * g) + xv;
      if (e2 < 4) r1[e2 & 3] = res; else r2[e2 & 3] = res;
    }
    *(f32x4*)(out + goff) = r1;
    *(f32x4*)(out + goff + 4) = r2;
  }
}

extern "C" void kernel_launch(void* const* d_in, const int* in_sizes, int n_in,
                              void* d_out, int out_size, void* d_ws, size_t ws_size,
                              hipStream_t stream) {
  (void)in_sizes; (void)n_in; (void)out_size; (void)ws_size;
  const float* x     = (const float*)d_in[0];
  const float* Wq    = (const float*)d_in[1];
  const float* bq    = (const float*)d_in[2];
  const float* Wk    = (const float*)d_in[3];
  const float* bk    = (const float*)d_in[4];
  const float* Wv    = (const float*)d_in[5];
  const float* bv    = (const float*)d_in[6];
  const float* eca   = (const float*)d_in[7];
  const float* gamma = (const float*)d_in[8];
  float* out = (float*)d_out;

  char* p = (char*)d_ws;
  auto take = [&](size_t bytes) {
    char* r = p;
    p += (bytes + 255) & ~(size_t)255;
    return r;
  };
  unsigned short* xpix  = (unsigned short*)take((size_t)BB * HWn * CC * 2);  // reused as vT
  unsigned short* qpix  = (unsigned short*)take((size_t)BB * HWn * CQP * 2);
  unsigned short* kpix  = (unsigned short*)take((size_t)BB * HWn * CQP * 2);
  unsigned short* vstd  = (unsigned short*)take((size_t)BB * CC * HWn * 2);
  unsigned short* outHT = (unsigned short*)take((size_t)BB * CC * HWn * 2);
  unsigned short* outWs = (unsigned short*)take((size_t)BB * CC * HWn * 2);
  float* mcol = (float*)take((size_t)BB * HWn * 4);
  float* scol = (float*)take((size_t)BB * HWn * 4);
  float* mrow = (float*)take((size_t)BB * HWn * 4);
  float* srow = (float*)take((size_t)BB * HWn * 4);
  float* mf   = (float*)take((size_t)BB * HWn * 4);
  float* rzf  = (float*)take((size_t)BB * HWn * 4);
  float* mg   = (float*)take((size_t)BB * HWn * 4);
  float* rzg  = (float*)take((size_t)BB * HWn * 4);
  unsigned short* Wcat = (unsigned short*)take((size_t)MR * CC * 2);
  float* bcat = (float*)take((size_t)MR * 4);
  float* y    = (float*)take((size_t)BB * CC * 4);
  float* gate = (float*)take((size_t)BB * CC * 4);
  unsigned short* vT = xpix;  // xpix dead after k_qkv; k_vT fills it as vT

  hipMemsetAsync(y, 0, (size_t)BB * CC * 4, stream);
  k_wcvt<<<dim3(128), dim3(256), 0, stream>>>(Wq, Wk, Wv, bq, bk, bv, Wcat, bcat);
  k_xT<<<dim3(2048), dim3(256), 0, stream>>>(x, xpix, y);
  k_gate<<<dim3(9), dim3(256), 0, stream>>>(y, eca, gate);
  k_qkv<<<dim3(1536), dim3(256), 0, stream>>>(xpix, Wcat, bcat, vstd, qpix, kpix);
  k_vT<<<dim3(4608), dim3(256), 0, stream>>>(vstd, vT);
  k_stats<<<dim3(1024), dim3(256), 0, stream>>>(qpix, kpix, mcol, scol, 0);
  k_stats<<<dim3(1024), dim3(256), 0, stream>>>(qpix, kpix, mrow, srow, 1);
  k_comb<<<dim3(512), dim3(256), 0, stream>>>(mcol, scol, mrow, srow, mf, rzf, mg, rzg);
  k_attout<<<dim3(1024), dim3(256), 0, stream>>>(qpix, kpix, vT, outHT, mf, rzf, 0);
  k_attout<<<dim3(1024), dim3(256), 0, stream>>>(qpix, kpix, vstd, outWs, mg, rzg, 1);
  k_final<<<dim3(BB * CC * 4), dim3(256), 0, stream>>>(outHT, outWs, x, gate, gamma, out);
}